// Round 1
// baseline (1090.316 us; speedup 1.0000x reference)
//
#include <hip/hip_runtime.h>

#define N_NODES 50000
#define N_EDGES 800000
#define F_INDIM 512
#define HID     256
#define N_CLS   64
#define K_STEPS 10
#define ALPHA_V 0.1f

// ---------------- edge dtype detection ----------------
// If edge_index is int64 (values < 50000 < 2^31), every odd 32-bit word is 0.
// If int32, odd words are random indices (P(all zero) ~ (1/50000)^1024 ~ 0).
__global__ void detect_kernel(const int* __restrict__ eb, int* __restrict__ flag) {
  __shared__ int any;
  if (threadIdx.x == 0) any = 0;
  __syncthreads();
  for (int j = threadIdx.x; j < 1024; j += 256) {
    if (eb[2 * j + 1] != 0) atomicOr(&any, 1);
  }
  __syncthreads();
  if (threadIdx.x == 0) flag[0] = any ? 0 : 1;  // shift: 1 => int64 stride, 0 => int32
}

// ---------------- degree histogram over targets ----------------
__global__ void count_kernel(const int* __restrict__ eb, const int* __restrict__ flagp,
                             int* __restrict__ cnt) {
  int e = blockIdx.x * 256 + threadIdx.x;
  if (e >= N_EDGES) return;
  int sh = flagp[0];
  int c = eb[((size_t)(N_EDGES + e)) << sh];
  atomicAdd(&cnt[c], 1);
}

// ---------------- 3-kernel exclusive scan of cnt -> ptr ----------------
__global__ void scan1_kernel(const int* __restrict__ cnt, int* __restrict__ ptr,
                             int* __restrict__ bsum) {
  __shared__ int sm[256];
  int t = threadIdx.x;
  int i = blockIdx.x * 256 + t;
  int v = (i < N_NODES) ? cnt[i] : 0;
  sm[t] = v;
  __syncthreads();
  for (int off = 1; off < 256; off <<= 1) {
    int x = sm[t];
    if (t >= off) x += sm[t - off];
    __syncthreads();
    sm[t] = x;
    __syncthreads();
  }
  int incl = sm[t];
  if (i < N_NODES) ptr[i] = incl - v;          // block-local exclusive
  if (t == 255) bsum[blockIdx.x] = incl;       // block total
}

__global__ void scan2_kernel(int* __restrict__ bsum, int nblk) {
  __shared__ int sm[256];
  int t = threadIdx.x;
  int v = (t < nblk) ? bsum[t] : 0;
  sm[t] = v;
  __syncthreads();
  for (int off = 1; off < 256; off <<= 1) {
    int x = sm[t];
    if (t >= off) x += sm[t - off];
    __syncthreads();
    sm[t] = x;
    __syncthreads();
  }
  int incl = sm[t];
  if (t < nblk) bsum[t] = incl - v;            // exclusive block offsets
}

__global__ void scan3_kernel(int* __restrict__ ptr, const int* __restrict__ bsum) {
  int i = blockIdx.x * 256 + threadIdx.x;
  if (i < N_NODES) ptr[i] += bsum[i >> 8];
  if (i == 0) ptr[N_NODES] = N_EDGES;
}

// ---------------- dinv + cursor init ----------------
__global__ void dinv_kernel(const int* __restrict__ cnt, const int* __restrict__ ptr,
                            float* __restrict__ dinv, int* __restrict__ cursor) {
  int i = blockIdx.x * 256 + threadIdx.x;
  if (i >= N_NODES) return;
  dinv[i] = rsqrtf((float)cnt[i] + 1.0f);      // +1 self-loop; always > 0
  cursor[i] = ptr[i];
}

// ---------------- CSR fill (by target), weight pre-scaled by (1-alpha) ----------------
__global__ void fill_kernel(const int* __restrict__ eb, const int* __restrict__ flagp,
                            const float* __restrict__ dinv, int* __restrict__ cursor,
                            int* __restrict__ esrc, float* __restrict__ ew) {
  int e = blockIdx.x * 256 + threadIdx.x;
  if (e >= N_EDGES) return;
  int sh = flagp[0];
  int r = eb[((size_t)e) << sh];
  int c = eb[((size_t)(N_EDGES + e)) << sh];
  int pos = atomicAdd(&cursor[c], 1);
  esrc[pos] = r;
  ew[pos] = (1.0f - ALPHA_V) * dinv[r] * dinv[c];
}

// ---------------- GEMM1: h = relu(x @ W1 + b1), tile 128x128, 8x8/thread ----------------
__global__ __launch_bounds__(256) void gemm1_kernel(const float* __restrict__ A,
    const float* __restrict__ B, const float* __restrict__ bias,
    float* __restrict__ C, int M) {
  __shared__ float As[8][128];
  __shared__ float Bs[8][128];
  const int t = threadIdx.x;
  const int row0 = blockIdx.x * 128;
  const int col0 = blockIdx.y * 128;
  const int ty = t >> 4, tx = t & 15;
  float acc[2][2][4][4] = {};
  const int ra = t >> 1, ka = (t & 1) * 4;
  const int kb = t >> 5, cb = (t & 31) * 4;
  for (int kt = 0; kt < F_INDIM; kt += 8) {
    float4 av = make_float4(0.f, 0.f, 0.f, 0.f);
    int grow = row0 + ra;
    if (grow < M) av = *(const float4*)(A + (size_t)grow * F_INDIM + kt + ka);
    As[ka + 0][ra] = av.x; As[ka + 1][ra] = av.y;
    As[ka + 2][ra] = av.z; As[ka + 3][ra] = av.w;
    *(float4*)(&Bs[kb][cb]) = *(const float4*)(B + (size_t)(kt + kb) * HID + col0 + cb);
    __syncthreads();
#pragma unroll
    for (int k = 0; k < 8; ++k) {
      float am[8], bv[8];
      *(float4*)(&am[0]) = *(const float4*)(&As[k][ty * 4]);
      *(float4*)(&am[4]) = *(const float4*)(&As[k][ty * 4 + 64]);
      *(float4*)(&bv[0]) = *(const float4*)(&Bs[k][tx * 4]);
      *(float4*)(&bv[4]) = *(const float4*)(&Bs[k][tx * 4 + 64]);
#pragma unroll
      for (int rh = 0; rh < 2; ++rh)
#pragma unroll
        for (int ch = 0; ch < 2; ++ch)
#pragma unroll
          for (int i = 0; i < 4; ++i)
#pragma unroll
            for (int j = 0; j < 4; ++j)
              acc[rh][ch][i][j] += am[rh * 4 + i] * bv[ch * 4 + j];
    }
    __syncthreads();
  }
#pragma unroll
  for (int rh = 0; rh < 2; ++rh)
#pragma unroll
    for (int i = 0; i < 4; ++i) {
      int grow = row0 + ty * 4 + rh * 64 + i;
      if (grow >= M) continue;
#pragma unroll
      for (int ch = 0; ch < 2; ++ch) {
        int gcol = col0 + tx * 4 + ch * 64;
        float4 o;
        o.x = fmaxf(acc[rh][ch][i][0] + bias[gcol + 0], 0.f);
        o.y = fmaxf(acc[rh][ch][i][1] + bias[gcol + 1], 0.f);
        o.z = fmaxf(acc[rh][ch][i][2] + bias[gcol + 2], 0.f);
        o.w = fmaxf(acc[rh][ch][i][3] + bias[gcol + 3], 0.f);
        *(float4*)(C + (size_t)grow * HID + gcol) = o;
      }
    }
}

// ---------------- GEMM2: x0 = h @ W2 + b2, tile 128x64 ----------------
__global__ __launch_bounds__(256) void gemm2_kernel(const float* __restrict__ A,
    const float* __restrict__ B, const float* __restrict__ bias,
    float* __restrict__ C, int M) {
  __shared__ float As[8][128];
  __shared__ float Bs[8][64];
  const int t = threadIdx.x;
  const int row0 = blockIdx.x * 128;
  const int ty = t >> 4, tx = t & 15;
  float acc[2][4][4] = {};
  const int ra = t >> 1, ka = (t & 1) * 4;
  for (int kt = 0; kt < HID; kt += 8) {
    float4 av = make_float4(0.f, 0.f, 0.f, 0.f);
    int grow = row0 + ra;
    if (grow < M) av = *(const float4*)(A + (size_t)grow * HID + kt + ka);
    As[ka + 0][ra] = av.x; As[ka + 1][ra] = av.y;
    As[ka + 2][ra] = av.z; As[ka + 3][ra] = av.w;
    if (t < 128) {
      int kb = t >> 4, cb2 = (t & 15) * 4;
      *(float4*)(&Bs[kb][cb2]) = *(const float4*)(B + (size_t)(kt + kb) * N_CLS + cb2);
    }
    __syncthreads();
#pragma unroll
    for (int k = 0; k < 8; ++k) {
      float am[8], bv[4];
      *(float4*)(&am[0]) = *(const float4*)(&As[k][ty * 4]);
      *(float4*)(&am[4]) = *(const float4*)(&As[k][ty * 4 + 64]);
      *(float4*)(&bv[0]) = *(const float4*)(&Bs[k][tx * 4]);
#pragma unroll
      for (int rh = 0; rh < 2; ++rh)
#pragma unroll
        for (int i = 0; i < 4; ++i)
#pragma unroll
          for (int j = 0; j < 4; ++j)
            acc[rh][i][j] += am[rh * 4 + i] * bv[j];
    }
    __syncthreads();
  }
#pragma unroll
  for (int rh = 0; rh < 2; ++rh)
#pragma unroll
    for (int i = 0; i < 4; ++i) {
      int grow = row0 + ty * 4 + rh * 64 + i;
      if (grow >= M) continue;
      float4 o;
      o.x = acc[rh][i][0] + bias[tx * 4 + 0];
      o.y = acc[rh][i][1] + bias[tx * 4 + 1];
      o.z = acc[rh][i][2] + bias[tx * 4 + 2];
      o.w = acc[rh][i][3] + bias[tx * 4 + 3];
      *(float4*)(C + (size_t)grow * N_CLS + tx * 4) = o;
    }
}

// ---------------- propagation: one wave per node, lane = channel ----------------
__global__ __launch_bounds__(256) void prop_kernel(const float* __restrict__ zin,
    const float* __restrict__ x0, const float* __restrict__ dinv,
    const int* __restrict__ ptr, const int* __restrict__ esrc,
    const float* __restrict__ ew, float* __restrict__ zout) {
  int wid = (blockIdx.x * 256 + threadIdx.x) >> 6;
  int lane = threadIdx.x & 63;
  if (wid >= N_NODES) return;
  float di = dinv[wid];
  // self-loop (weight (1-a)*dinv^2) + alpha * x0
  float acc = ALPHA_V * x0[wid * 64 + lane]
            + (1.0f - ALPHA_V) * di * di * zin[wid * 64 + lane];
  int e0 = ptr[wid], e1 = ptr[wid + 1];
  for (int e = e0; e < e1; ++e) {
    int s = esrc[e];
    float w = ew[e];  // pre-scaled by (1-alpha)
    acc += w * zin[s * 64 + lane];
  }
  zout[wid * 64 + lane] = acc;
}

// ---------------- host launcher ----------------
extern "C" void kernel_launch(void* const* d_in, const int* in_sizes, int n_in,
                              void* d_out, int out_size, void* d_ws, size_t ws_size,
                              hipStream_t stream) {
  const float* x  = (const float*)d_in[0];
  const float* W1 = (const float*)d_in[1];
  const float* b1 = (const float*)d_in[2];
  const float* W2 = (const float*)d_in[3];
  const float* b2 = (const float*)d_in[4];
  const int*   eb = (const int*)d_in[5];
  float* out = (float*)d_out;

  char* ws = (char*)d_ws;
  size_t off = 0;
  auto alloc = [&](size_t bytes) -> void* {
    void* p = ws + off;
    off = (off + bytes + 255) & ~(size_t)255;
    return p;
  };

  int*   flagp  = (int*)alloc(256);
  int*   cnt    = (int*)alloc(N_NODES * sizeof(int));
  int*   ptr    = (int*)alloc((N_NODES + 1) * sizeof(int));
  int*   cursor = (int*)alloc(N_NODES * sizeof(int));
  int*   bsum   = (int*)alloc(256 * sizeof(int));
  float* dinv   = (float*)alloc(N_NODES * sizeof(float));
  int*   esrc   = (int*)alloc(N_EDGES * sizeof(int));
  float* ew     = (float*)alloc(N_EDGES * sizeof(float));
  float* x0     = (float*)alloc((size_t)N_NODES * N_CLS * sizeof(float));
  float* zB     = (float*)alloc((size_t)N_NODES * N_CLS * sizeof(float));

  // adaptive chunking of the h intermediate to fit ws
  int nchunks = 1;
  while (nchunks < 16) {
    size_t hbytes = (size_t)(N_NODES / nchunks) * HID * sizeof(float);
    if (off + hbytes <= ws_size) break;
    nchunks <<= 1;
  }
  int Mc = N_NODES / nchunks;
  float* h = (float*)alloc((size_t)Mc * HID * sizeof(float));

  hipMemsetAsync(cnt, 0, N_NODES * sizeof(int), stream);
  detect_kernel<<<1, 256, 0, stream>>>(eb, flagp);
  count_kernel<<<(N_EDGES + 255) / 256, 256, 0, stream>>>(eb, flagp, cnt);
  int nblk = (N_NODES + 255) / 256;  // 196
  scan1_kernel<<<nblk, 256, 0, stream>>>(cnt, ptr, bsum);
  scan2_kernel<<<1, 256, 0, stream>>>(bsum, nblk);
  scan3_kernel<<<nblk, 256, 0, stream>>>(ptr, bsum);
  dinv_kernel<<<nblk, 256, 0, stream>>>(cnt, ptr, dinv, cursor);
  fill_kernel<<<(N_EDGES + 255) / 256, 256, 0, stream>>>(eb, flagp, dinv, cursor, esrc, ew);

  for (int ci = 0; ci < nchunks; ++ci) {
    const float* Achunk = x + (size_t)ci * Mc * F_INDIM;
    dim3 g1((Mc + 127) / 128, HID / 128);
    gemm1_kernel<<<g1, 256, 0, stream>>>(Achunk, W1, b1, h, Mc);
    dim3 g2((Mc + 127) / 128, 1);
    gemm2_kernel<<<g2, 256, 0, stream>>>(h, W2, b2, x0 + (size_t)ci * Mc * N_CLS, Mc);
  }

  int pgrid = (N_NODES * 64) / 256;  // one wave per node, 4 waves/block
  const float* zin = x0;
  float* zout = zB;
  for (int s = 0; s < K_STEPS; ++s) {
    prop_kernel<<<pgrid, 256, 0, stream>>>(zin, x0, dinv, ptr, esrc, ew, zout);
    zin = zout;
    zout = (zout == zB) ? out : zB;
  }
}

// Round 2
// 531.855 us; speedup vs baseline: 2.0500x; 2.0500x over previous
//
#include <hip/hip_runtime.h>

#define N_NODES 50000
#define N_EDGES 800000
#define F_INDIM 512
#define HID     256
#define N_CLS   64
#define K_STEPS 10
#define ALPHA_V 0.1f

typedef __attribute__((ext_vector_type(8))) short short8;
typedef __attribute__((ext_vector_type(4))) float f32x4;

__device__ __forceinline__ unsigned short f2bf(float f) {
  unsigned u = __builtin_bit_cast(unsigned, f);
  unsigned r = (u + 0x7fffu + ((u >> 16) & 1u)) >> 16;
  return (unsigned short)r;
}

#define GLOAD_LDS16(g, l)                                                        \
  __builtin_amdgcn_global_load_lds(                                              \
      (const __attribute__((address_space(1))) unsigned int*)(g),                \
      (__attribute__((address_space(3))) unsigned int*)(l), 16, 0, 0)

// ---------------- edge dtype detection ----------------
__global__ void detect_kernel(const int* __restrict__ eb, int* __restrict__ flag) {
  __shared__ int any;
  if (threadIdx.x == 0) any = 0;
  __syncthreads();
  for (int j = threadIdx.x; j < 1024; j += 256) {
    if (eb[2 * j + 1] != 0) atomicOr(&any, 1);
  }
  __syncthreads();
  if (threadIdx.x == 0) flag[0] = any ? 0 : 1;  // 1 => int64 stride, 0 => int32
}

// ---------------- degree histogram over targets ----------------
__global__ void count_kernel(const int* __restrict__ eb, const int* __restrict__ flagp,
                             int* __restrict__ cnt) {
  int e = blockIdx.x * 256 + threadIdx.x;
  if (e >= N_EDGES) return;
  int sh = flagp[0];
  int c = eb[((size_t)(N_EDGES + e)) << sh];
  atomicAdd(&cnt[c], 1);
}

// ---------------- 3-kernel exclusive scan ----------------
__global__ void scan1_kernel(const int* __restrict__ cnt, int* __restrict__ ptr,
                             int* __restrict__ bsum) {
  __shared__ int sm[256];
  int t = threadIdx.x;
  int i = blockIdx.x * 256 + t;
  int v = (i < N_NODES) ? cnt[i] : 0;
  sm[t] = v;
  __syncthreads();
  for (int off = 1; off < 256; off <<= 1) {
    int x = sm[t];
    if (t >= off) x += sm[t - off];
    __syncthreads();
    sm[t] = x;
    __syncthreads();
  }
  int incl = sm[t];
  if (i < N_NODES) ptr[i] = incl - v;
  if (t == 255) bsum[blockIdx.x] = incl;
}

__global__ void scan2_kernel(int* __restrict__ bsum, int nblk) {
  __shared__ int sm[256];
  int t = threadIdx.x;
  int v = (t < nblk) ? bsum[t] : 0;
  sm[t] = v;
  __syncthreads();
  for (int off = 1; off < 256; off <<= 1) {
    int x = sm[t];
    if (t >= off) x += sm[t - off];
    __syncthreads();
    sm[t] = x;
    __syncthreads();
  }
  int incl = sm[t];
  if (t < nblk) bsum[t] = incl - v;
}

__global__ void scan3_kernel(int* __restrict__ ptr, const int* __restrict__ bsum) {
  int i = blockIdx.x * 256 + threadIdx.x;
  if (i < N_NODES) ptr[i] += bsum[i >> 8];
  if (i == 0) ptr[N_NODES] = N_EDGES;
}

// ---------------- dinv + selfw + cursor init ----------------
__global__ void dinv_kernel(const int* __restrict__ cnt, const int* __restrict__ ptr,
                            float* __restrict__ dinv, float* __restrict__ selfw,
                            int* __restrict__ cursor) {
  int i = blockIdx.x * 256 + threadIdx.x;
  if (i >= N_NODES) return;
  float di = rsqrtf((float)cnt[i] + 1.0f);
  dinv[i] = di;
  selfw[i] = (1.0f - ALPHA_V) * di * di;
  cursor[i] = ptr[i];
}

// ---------------- CSR fill (by target), packed (src, weight) ----------------
__global__ void fill_kernel(const int* __restrict__ eb, const int* __restrict__ flagp,
                            const float* __restrict__ dinv, int* __restrict__ cursor,
                            int2* __restrict__ epack) {
  int e = blockIdx.x * 256 + threadIdx.x;
  if (e >= N_EDGES) return;
  int sh = flagp[0];
  int r = eb[((size_t)e) << sh];
  int c = eb[((size_t)(N_EDGES + e)) << sh];
  int pos = atomicAdd(&cursor[c], 1);
  float w = (1.0f - ALPHA_V) * dinv[r] * dinv[c];
  epack[pos] = make_int2(r, __float_as_int(w));
}

// ---------------- weight transpose + bf16 prepass ----------------
__global__ void prep_w(const float* __restrict__ W1, const float* __restrict__ W2,
                       unsigned short* __restrict__ W1T, unsigned short* __restrict__ W2T) {
  int i = blockIdx.x * 256 + threadIdx.x;
  if (i < F_INDIM * HID) {
    int k = i >> 8, c = i & 255;
    W1T[(size_t)c * F_INDIM + k] = f2bf(W1[i]);
  }
  int j = i - F_INDIM * HID;
  if (j >= 0 && j < HID * N_CLS) {
    int k = j >> 6, c = j & 63;
    W2T[(size_t)c * HID + k] = f2bf(W2[j]);
  }
}

// ---------------- GEMM1: h = relu(x @ W1 + b1), bf16 MFMA ----------------
// A: x fp32 [M][512] (converted in staging), BT: W1^T bf16 [256][512]
// out H bf16 [M][256]. Tiles 128x128x64, double-buffered, 4 waves (2x2).
__global__ __launch_bounds__(256, 2) void gemm1_mfma(
    const float* __restrict__ A, const unsigned short* __restrict__ BT,
    const float* __restrict__ bias, unsigned short* __restrict__ H, int M) {
  __shared__ short8 As[2][128 * 8];
  __shared__ short8 Bs[2][128 * 8];
  const int t = threadIdx.x;
  const int wave = t >> 6, lane = t & 63;
  const int wr = wave >> 1, wc = wave & 1;
  const int row0 = blockIdx.x * 128, col0 = blockIdx.y * 128;
  const int sr8 = lane >> 3, ss = lane & 7;

  f32x4 acc[4][4];
#pragma unroll
  for (int m = 0; m < 4; ++m)
#pragma unroll
    for (int n = 0; n < 4; ++n) acc[m][n] = (f32x4)0.0f;

  const int NT = F_INDIM / 64;  // 8

  auto stageB = [&](int buf, int kt) {
    int k0 = kt * 64;
#pragma unroll
    for (int p = 0; p < 4; ++p) {
      int rb = p * 32 + wave * 8 + sr8;
      int srck = ss ^ (rb & 7);
      const unsigned short* g = BT + (size_t)(col0 + rb) * F_INDIM + k0 + srck * 8;
      short8* lb = &Bs[buf][(p * 32 + wave * 8) * 8];
      GLOAD_LDS16(g, lb);
    }
  };
  auto loadA = [&](int kt, f32x4 (&ar)[4][2]) {
    int k0 = kt * 64;
#pragma unroll
    for (int p = 0; p < 4; ++p) {
      int r = p * 32 + wave * 8 + sr8;
      int gr = row0 + r;
      if (gr > M - 1) gr = M - 1;
      int srck = ss ^ (r & 7);
      const f32x4* g = (const f32x4*)(A + (size_t)gr * F_INDIM + k0 + srck * 8);
      ar[p][0] = g[0];
      ar[p][1] = g[1];
    }
  };
  auto writeA = [&](int buf, f32x4 (&ar)[4][2]) {
#pragma unroll
    for (int p = 0; p < 4; ++p) {
      int r = p * 32 + wave * 8 + sr8;
      short8 o;
#pragma unroll
      for (int j = 0; j < 4; ++j) {
        o[j] = (short)f2bf(ar[p][0][j]);
        o[4 + j] = (short)f2bf(ar[p][1][j]);
      }
      As[buf][r * 8 + ss] = o;
    }
  };
  auto compute = [&](int buf) {
#pragma unroll
    for (int ks = 0; ks < 2; ++ks) {
      int kc = ks * 4 + (lane >> 4);
      short8 af[4], bf[4];
#pragma unroll
      for (int m = 0; m < 4; ++m) {
        int r = wr * 64 + m * 16 + (lane & 15);
        af[m] = As[buf][r * 8 + (kc ^ (r & 7))];
      }
#pragma unroll
      for (int n = 0; n < 4; ++n) {
        int c = wc * 64 + n * 16 + (lane & 15);
        bf[n] = Bs[buf][c * 8 + (kc ^ (c & 7))];
      }
#pragma unroll
      for (int m = 0; m < 4; ++m)
#pragma unroll
        for (int n = 0; n < 4; ++n)
          acc[m][n] = __builtin_amdgcn_mfma_f32_16x16x32_bf16(af[m], bf[n], acc[m][n], 0, 0, 0);
    }
  };

  {
    f32x4 ar0[4][2];
    loadA(0, ar0);
    stageB(0, 0);
    writeA(0, ar0);
  }
  __syncthreads();
  for (int kt = 0; kt < NT; ++kt) {
    int cur = kt & 1;
    f32x4 ar[4][2];
    if (kt + 1 < NT) {
      stageB(cur ^ 1, kt + 1);
      loadA(kt + 1, ar);
    }
    compute(cur);
    if (kt + 1 < NT) writeA(cur ^ 1, ar);
    __syncthreads();
  }

  const int erow = wr * 64 + (lane >> 4) * 4;
  const int ecol = wc * 64 + (lane & 15);
#pragma unroll
  for (int m = 0; m < 4; ++m)
#pragma unroll
    for (int i = 0; i < 4; ++i) {
      int grow = row0 + erow + m * 16 + i;
      if (grow >= M) continue;
#pragma unroll
      for (int n = 0; n < 4; ++n) {
        int gcol = col0 + ecol + n * 16;
        float v = acc[m][n][i] + bias[gcol];
        v = fmaxf(v, 0.0f);
        H[(size_t)grow * HID + gcol] = f2bf(v);
      }
    }
}

// ---------------- GEMM2: x0 = h @ W2 + b2, bf16 MFMA ----------------
// A: h bf16 [M][256], BT: W2^T bf16 [64][256], out fp32 [M][64]
// Tiles 128x64x64, double-buffered, 4 waves (rows split).
__global__ __launch_bounds__(256, 2) void gemm2_mfma(
    const unsigned short* __restrict__ Hm, const unsigned short* __restrict__ BT,
    const float* __restrict__ bias, float* __restrict__ C, int M) {
  __shared__ short8 As[2][128 * 8];
  __shared__ short8 Bs[2][64 * 8];
  const int t = threadIdx.x;
  const int wave = t >> 6, lane = t & 63;
  const int row0 = blockIdx.x * 128;
  const int sr8 = lane >> 3, ss = lane & 7;

  f32x4 acc[2][4];
#pragma unroll
  for (int m = 0; m < 2; ++m)
#pragma unroll
    for (int n = 0; n < 4; ++n) acc[m][n] = (f32x4)0.0f;

  const int NT = HID / 64;  // 4

  auto stageA = [&](int buf, int kt) {
    int k0 = kt * 64;
#pragma unroll
    for (int p = 0; p < 4; ++p) {
      int r = p * 32 + wave * 8 + sr8;
      int gr = row0 + r;
      if (gr > M - 1) gr = M - 1;
      int srck = ss ^ (r & 7);
      const unsigned short* g = Hm + (size_t)gr * HID + k0 + srck * 8;
      short8* lb = &As[buf][(p * 32 + wave * 8) * 8];
      GLOAD_LDS16(g, lb);
    }
  };
  auto stageB = [&](int buf, int kt) {
    int k0 = kt * 64;
#pragma unroll
    for (int p = 0; p < 2; ++p) {
      int rb = p * 32 + wave * 8 + sr8;
      int srck = ss ^ (rb & 7);
      const unsigned short* g = BT + (size_t)rb * HID + k0 + srck * 8;
      short8* lb = &Bs[buf][(p * 32 + wave * 8) * 8];
      GLOAD_LDS16(g, lb);
    }
  };
  auto compute = [&](int buf) {
#pragma unroll
    for (int ks = 0; ks < 2; ++ks) {
      int kc = ks * 4 + (lane >> 4);
      short8 af[2], bf[4];
#pragma unroll
      for (int m = 0; m < 2; ++m) {
        int r = wave * 32 + m * 16 + (lane & 15);
        af[m] = As[buf][r * 8 + (kc ^ (r & 7))];
      }
#pragma unroll
      for (int n = 0; n < 4; ++n) {
        int c = n * 16 + (lane & 15);
        bf[n] = Bs[buf][c * 8 + (kc ^ (c & 7))];
      }
#pragma unroll
      for (int m = 0; m < 2; ++m)
#pragma unroll
        for (int n = 0; n < 4; ++n)
          acc[m][n] = __builtin_amdgcn_mfma_f32_16x16x32_bf16(af[m], bf[n], acc[m][n], 0, 0, 0);
    }
  };

  stageA(0, 0);
  stageB(0, 0);
  __syncthreads();
  for (int kt = 0; kt < NT; ++kt) {
    int cur = kt & 1;
    if (kt + 1 < NT) {
      stageA(cur ^ 1, kt + 1);
      stageB(cur ^ 1, kt + 1);
    }
    compute(cur);
    __syncthreads();
  }

  const int erow = wave * 32 + (lane >> 4) * 4;
  const int ecol = lane & 15;
#pragma unroll
  for (int m = 0; m < 2; ++m)
#pragma unroll
    for (int i = 0; i < 4; ++i) {
      int grow = row0 + erow + m * 16 + i;
      if (grow >= M) continue;
#pragma unroll
      for (int n = 0; n < 4; ++n) {
        int gcol = ecol + n * 16;
        C[(size_t)grow * N_CLS + gcol] = acc[m][n][i] + bias[gcol];
      }
    }
}

// ---------------- propagation: one wave per node, lane = channel ----------------
__global__ __launch_bounds__(256) void prop_kernel(const float* __restrict__ zin,
    const float* __restrict__ x0, const float* __restrict__ selfw,
    const int* __restrict__ ptr, const int2* __restrict__ epack,
    float* __restrict__ zout) {
  int wid = (blockIdx.x * 256 + threadIdx.x) >> 6;
  int lane = threadIdx.x & 63;
  if (wid >= N_NODES) return;
  size_t base = (size_t)wid * 64 + lane;
  float acc = fmaf(selfw[wid], zin[base], ALPHA_V * x0[base]);
  int e = ptr[wid], e1 = ptr[wid + 1];
  for (; e + 4 <= e1; e += 4) {
    int2 p0 = epack[e], p1 = epack[e + 1], p2 = epack[e + 2], p3 = epack[e + 3];
    float g0 = zin[(size_t)p0.x * 64 + lane];
    float g1 = zin[(size_t)p1.x * 64 + lane];
    float g2 = zin[(size_t)p2.x * 64 + lane];
    float g3 = zin[(size_t)p3.x * 64 + lane];
    acc = fmaf(__int_as_float(p0.y), g0, acc);
    acc = fmaf(__int_as_float(p1.y), g1, acc);
    acc = fmaf(__int_as_float(p2.y), g2, acc);
    acc = fmaf(__int_as_float(p3.y), g3, acc);
  }
  for (; e < e1; ++e) {
    int2 p = epack[e];
    acc = fmaf(__int_as_float(p.y), zin[(size_t)p.x * 64 + lane], acc);
  }
  zout[base] = acc;
}

// ---------------- host launcher ----------------
extern "C" void kernel_launch(void* const* d_in, const int* in_sizes, int n_in,
                              void* d_out, int out_size, void* d_ws, size_t ws_size,
                              hipStream_t stream) {
  const float* x  = (const float*)d_in[0];
  const float* W1 = (const float*)d_in[1];
  const float* b1 = (const float*)d_in[2];
  const float* W2 = (const float*)d_in[3];
  const float* b2 = (const float*)d_in[4];
  const int*   eb = (const int*)d_in[5];
  float* out = (float*)d_out;

  char* ws = (char*)d_ws;
  size_t off = 0;
  auto alloc = [&](size_t bytes) -> void* {
    void* p = ws + off;
    off = (off + bytes + 255) & ~(size_t)255;
    return p;
  };

  int*   flagp  = (int*)alloc(256);
  int*   cnt    = (int*)alloc(N_NODES * sizeof(int));
  int*   ptr    = (int*)alloc((N_NODES + 1) * sizeof(int));
  int*   cursor = (int*)alloc(N_NODES * sizeof(int));
  int*   bsum   = (int*)alloc(256 * sizeof(int));
  float* dinv   = (float*)alloc(N_NODES * sizeof(float));
  float* selfw  = (float*)alloc(N_NODES * sizeof(float));
  int2*  epack  = (int2*)alloc((size_t)N_EDGES * sizeof(int2));
  unsigned short* W1T = (unsigned short*)alloc((size_t)HID * F_INDIM * sizeof(unsigned short));
  unsigned short* W2T = (unsigned short*)alloc((size_t)N_CLS * HID * sizeof(unsigned short));
  float* x0     = (float*)alloc((size_t)N_NODES * N_CLS * sizeof(float));
  float* zB     = (float*)alloc((size_t)N_NODES * N_CLS * sizeof(float));

  int nchunks = 1;
  while (nchunks < 16) {
    size_t hbytes = (size_t)(N_NODES / nchunks) * HID * sizeof(unsigned short);
    if (off + hbytes <= ws_size) break;
    nchunks <<= 1;
  }
  int Mc = N_NODES / nchunks;
  unsigned short* h = (unsigned short*)alloc((size_t)Mc * HID * sizeof(unsigned short));

  hipMemsetAsync(cnt, 0, N_NODES * sizeof(int), stream);
  detect_kernel<<<1, 256, 0, stream>>>(eb, flagp);
  count_kernel<<<(N_EDGES + 255) / 256, 256, 0, stream>>>(eb, flagp, cnt);
  int nblk = (N_NODES + 255) / 256;
  scan1_kernel<<<nblk, 256, 0, stream>>>(cnt, ptr, bsum);
  scan2_kernel<<<1, 256, 0, stream>>>(bsum, nblk);
  scan3_kernel<<<nblk, 256, 0, stream>>>(ptr, bsum);
  dinv_kernel<<<nblk, 256, 0, stream>>>(cnt, ptr, dinv, selfw, cursor);
  fill_kernel<<<(N_EDGES + 255) / 256, 256, 0, stream>>>(eb, flagp, dinv, cursor, epack);
  prep_w<<<(F_INDIM * HID + HID * N_CLS + 255) / 256, 256, 0, stream>>>(W1, W2, W1T, W2T);

  for (int ci = 0; ci < nchunks; ++ci) {
    const float* Achunk = x + (size_t)ci * Mc * F_INDIM;
    dim3 g1((Mc + 127) / 128, HID / 128);
    gemm1_mfma<<<g1, 256, 0, stream>>>(Achunk, W1T, b1, h, Mc);
    dim3 g2((Mc + 127) / 128, 1);
    gemm2_mfma<<<g2, 256, 0, stream>>>(h, W2T, b2, x0 + (size_t)ci * Mc * N_CLS, Mc);
  }

  int pgrid = (N_NODES * 64) / 256;
  const float* zin = x0;
  float* zout = zB;
  for (int s = 0; s < K_STEPS; ++s) {
    prop_kernel<<<pgrid, 256, 0, stream>>>(zin, x0, selfw, ptr, epack, zout);
    zin = zout;
    zout = (zout == zB) ? out : zB;
  }
}

// Round 3
// 500.658 us; speedup vs baseline: 2.1778x; 1.0623x over previous
//
#include <hip/hip_runtime.h>

#define N_NODES 50000
#define N_EDGES 800000
#define F_INDIM 512
#define HID     256
#define N_CLS   64
#define K_STEPS 10
#define ALPHA_V 0.1f

typedef __attribute__((ext_vector_type(8))) short short8;
typedef __attribute__((ext_vector_type(4))) float f32x4;

__device__ __forceinline__ unsigned short f2bf(float f) {
  unsigned u = __builtin_bit_cast(unsigned, f);
  unsigned r = (u + 0x7fffu + ((u >> 16) & 1u)) >> 16;
  return (unsigned short)r;
}

#define GLOAD_LDS16(g, l)                                                        \
  __builtin_amdgcn_global_load_lds(                                              \
      (const __attribute__((address_space(1))) unsigned int*)(g),                \
      (__attribute__((address_space(3))) unsigned int*)(l), 16, 0, 0)

// ---------------- edge dtype detection ----------------
__global__ void detect_kernel(const int* __restrict__ eb, int* __restrict__ flag) {
  __shared__ int any;
  if (threadIdx.x == 0) any = 0;
  __syncthreads();
  for (int j = threadIdx.x; j < 1024; j += 256) {
    if (eb[2 * j + 1] != 0) atomicOr(&any, 1);
  }
  __syncthreads();
  if (threadIdx.x == 0) flag[0] = any ? 0 : 1;  // 1 => int64 stride, 0 => int32
}

// ---------------- degree histogram over targets ----------------
__global__ void count_kernel(const int* __restrict__ eb, const int* __restrict__ flagp,
                             int* __restrict__ cnt) {
  int e = blockIdx.x * 256 + threadIdx.x;
  if (e >= N_EDGES) return;
  int sh = flagp[0];
  int c = eb[((size_t)(N_EDGES + e)) << sh];
  atomicAdd(&cnt[c], 1);
}

// ---------------- 3-kernel exclusive scan ----------------
__global__ void scan1_kernel(const int* __restrict__ cnt, int* __restrict__ ptr,
                             int* __restrict__ bsum) {
  __shared__ int sm[256];
  int t = threadIdx.x;
  int i = blockIdx.x * 256 + t;
  int v = (i < N_NODES) ? cnt[i] : 0;
  sm[t] = v;
  __syncthreads();
  for (int off = 1; off < 256; off <<= 1) {
    int x = sm[t];
    if (t >= off) x += sm[t - off];
    __syncthreads();
    sm[t] = x;
    __syncthreads();
  }
  int incl = sm[t];
  if (i < N_NODES) ptr[i] = incl - v;
  if (t == 255) bsum[blockIdx.x] = incl;
}

__global__ void scan2_kernel(int* __restrict__ bsum, int nblk) {
  __shared__ int sm[256];
  int t = threadIdx.x;
  int v = (t < nblk) ? bsum[t] : 0;
  sm[t] = v;
  __syncthreads();
  for (int off = 1; off < 256; off <<= 1) {
    int x = sm[t];
    if (t >= off) x += sm[t - off];
    __syncthreads();
    sm[t] = x;
    __syncthreads();
  }
  int incl = sm[t];
  if (t < nblk) bsum[t] = incl - v;
}

__global__ void scan3_kernel(int* __restrict__ ptr, const int* __restrict__ bsum) {
  int i = blockIdx.x * 256 + threadIdx.x;
  if (i < N_NODES) ptr[i] += bsum[i >> 8];
  if (i == 0) ptr[N_NODES] = N_EDGES;
}

// ---------------- dinv + selfw + cursor init ----------------
__global__ void dinv_kernel(const int* __restrict__ cnt, const int* __restrict__ ptr,
                            float* __restrict__ dinv, float* __restrict__ selfw,
                            int* __restrict__ cursor) {
  int i = blockIdx.x * 256 + threadIdx.x;
  if (i >= N_NODES) return;
  float di = rsqrtf((float)cnt[i] + 1.0f);
  dinv[i] = di;
  selfw[i] = (1.0f - ALPHA_V) * di * di;
  cursor[i] = ptr[i];
}

// ---------------- CSR fill (by target), packed (src, weight) ----------------
__global__ void fill_kernel(const int* __restrict__ eb, const int* __restrict__ flagp,
                            const float* __restrict__ dinv, int* __restrict__ cursor,
                            int2* __restrict__ epack) {
  int e = blockIdx.x * 256 + threadIdx.x;
  if (e >= N_EDGES) return;
  int sh = flagp[0];
  int r = eb[((size_t)e) << sh];
  int c = eb[((size_t)(N_EDGES + e)) << sh];
  int pos = atomicAdd(&cursor[c], 1);
  float w = (1.0f - ALPHA_V) * dinv[r] * dinv[c];
  epack[pos] = make_int2(r, __float_as_int(w));
}

// ---------------- weight transpose + bf16 prepass ----------------
__global__ void prep_w(const float* __restrict__ W1, const float* __restrict__ W2,
                       unsigned short* __restrict__ W1T, unsigned short* __restrict__ W2T) {
  int i = blockIdx.x * 256 + threadIdx.x;
  if (i < F_INDIM * HID) {
    int k = i >> 8, c = i & 255;
    W1T[(size_t)c * F_INDIM + k] = f2bf(W1[i]);
  }
  int j = i - F_INDIM * HID;
  if (j >= 0 && j < HID * N_CLS) {
    int k = j >> 6, c = j & 63;
    W2T[(size_t)c * HID + k] = f2bf(W2[j]);
  }
}

// ---------------- GEMM1: h = relu(x @ W1 + b1), bf16 MFMA ----------------
// A: x fp32 [M][512] loaded straight to registers (MFMA layout) + in-reg cvt.
// B: W1^T bf16 [256][512] via global_load_lds, XOR-swizzled, double-buffered.
// 4 waves = 4 row-strips of 32 rows x 128 cols. One barrier per K-tile.
__global__ __launch_bounds__(256) void gemm1_mfma(
    const float* __restrict__ A, const unsigned short* __restrict__ BT,
    const float* __restrict__ bias, unsigned short* __restrict__ H, int M) {
  __shared__ short8 Bs[2][128 * 8];
  const int t = threadIdx.x;
  const int wave = t >> 6, lane = t & 63;
  const int row0 = blockIdx.x * 128, col0 = blockIdx.y * 128;
  const int sr8 = lane >> 3, ss = lane & 7;
  const int l15 = lane & 15, l4 = lane >> 4;

  f32x4 acc[2][8];
#pragma unroll
  for (int m = 0; m < 2; ++m)
#pragma unroll
    for (int n = 0; n < 8; ++n) acc[m][n] = (f32x4)0.0f;

  const int NT = F_INDIM / 64;  // 8

  auto stageB = [&](int buf, int kt) {
    int k0 = kt * 64;
#pragma unroll
    for (int p = 0; p < 4; ++p) {
      int rb = p * 32 + wave * 8 + sr8;
      int srck = ss ^ (rb & 7);
      const unsigned short* g = BT + (size_t)(col0 + rb) * F_INDIM + k0 + srck * 8;
      short8* lb = &Bs[buf][(p * 32 + wave * 8) * 8];
      GLOAD_LDS16(g, lb);
    }
  };

  f32x4 ar[2][2][2];  // [m][ks][half] raw fp32 A prefetch
  auto loadA = [&](int kt) {
    int k0 = kt * 64;
#pragma unroll
    for (int m = 0; m < 2; ++m) {
      int gr = row0 + wave * 32 + m * 16 + l15;
      if (gr > M - 1) gr = M - 1;
      const float* rp = A + (size_t)gr * F_INDIM + k0 + l4 * 8;
#pragma unroll
      for (int ks = 0; ks < 2; ++ks) {
        ar[m][ks][0] = *(const f32x4*)(rp + ks * 32);
        ar[m][ks][1] = *(const f32x4*)(rp + ks * 32 + 4);
      }
    }
  };
  short8 af[2][2];
  auto cvtA = [&]() {
#pragma unroll
    for (int m = 0; m < 2; ++m)
#pragma unroll
      for (int ks = 0; ks < 2; ++ks) {
        short8 o;
#pragma unroll
        for (int j = 0; j < 4; ++j) {
          o[j] = (short)f2bf(ar[m][ks][0][j]);
          o[4 + j] = (short)f2bf(ar[m][ks][1][j]);
        }
        af[m][ks] = o;
      }
  };
  auto compute = [&](int buf) {
#pragma unroll
    for (int ks = 0; ks < 2; ++ks) {
      int kc = ks * 4 + l4;
      short8 bf[8];
#pragma unroll
      for (int n = 0; n < 8; ++n) {
        int c = n * 16 + l15;
        bf[n] = Bs[buf][c * 8 + (kc ^ (c & 7))];
      }
#pragma unroll
      for (int m = 0; m < 2; ++m)
#pragma unroll
        for (int n = 0; n < 8; ++n)
          acc[m][n] = __builtin_amdgcn_mfma_f32_16x16x32_bf16(af[m][ks], bf[n], acc[m][n], 0, 0, 0);
    }
  };

  stageB(0, 0);
  loadA(0);
  __syncthreads();   // Bs[0] staged (vmcnt drained)
  cvtA();            // af ready for kt=0
#pragma unroll
  for (int kt = 0; kt < NT; ++kt) {
    if (kt + 1 < NT) {
      stageB((kt + 1) & 1, kt + 1);  // async into other buffer
      loadA(kt + 1);                 // prefetch A regs for next tile
    }
    compute(kt & 1);                 // uses af (this tile), Bs[cur]
    if (kt + 1 < NT) cvtA();         // convert prefetched A
    __syncthreads();                 // drains staging, guards buffer reuse
  }

  // epilogue: C/D layout col=lane&15, row=(lane>>4)*4+reg
  float bv[8];
#pragma unroll
  for (int n = 0; n < 8; ++n) bv[n] = bias[col0 + n * 16 + l15];
#pragma unroll
  for (int m = 0; m < 2; ++m)
#pragma unroll
    for (int i = 0; i < 4; ++i) {
      int grow = row0 + wave * 32 + m * 16 + l4 * 4 + i;
      if (grow >= M) continue;
#pragma unroll
      for (int n = 0; n < 8; ++n) {
        int gcol = col0 + n * 16 + l15;
        float v = fmaxf(acc[m][n][i] + bv[n], 0.0f);
        H[(size_t)grow * HID + gcol] = f2bf(v);
      }
    }
}

// ---------------- GEMM2: x0 = h @ W2 + b2, bf16 MFMA, no LDS ----------------
// A: h bf16 (direct short8 fragment loads). B: W2^T (32 KB, L1/L2-resident).
// One wave per 16 rows; block = 64 rows; grid = 782.
__global__ __launch_bounds__(256) void gemm2_mfma(
    const unsigned short* __restrict__ Hm, const unsigned short* __restrict__ BT,
    const float* __restrict__ bias, float* __restrict__ C, int M) {
  const int t = threadIdx.x;
  const int wave = t >> 6, lane = t & 63;
  const int l15 = lane & 15, l4 = lane >> 4;
  const int row0 = blockIdx.x * 64 + wave * 16;

  f32x4 acc[4];
#pragma unroll
  for (int n = 0; n < 4; ++n) acc[n] = (f32x4)0.0f;

  int gr = row0 + l15;
  if (gr > M - 1) gr = M - 1;
  const unsigned short* arow = Hm + (size_t)gr * HID + l4 * 8;

#pragma unroll
  for (int kt = 0; kt < HID / 32; ++kt) {  // 8 K-tiles of 32
    short8 af = *(const short8*)(arow + kt * 32);
    short8 bf[4];
#pragma unroll
    for (int n = 0; n < 4; ++n)
      bf[n] = *(const short8*)(BT + (size_t)(n * 16 + l15) * HID + kt * 32 + l4 * 8);
#pragma unroll
    for (int n = 0; n < 4; ++n)
      acc[n] = __builtin_amdgcn_mfma_f32_16x16x32_bf16(af, bf[n], acc[n], 0, 0, 0);
  }

#pragma unroll
  for (int n = 0; n < 4; ++n) {
    float bv = bias[n * 16 + l15];
#pragma unroll
    for (int i = 0; i < 4; ++i) {
      int grow = row0 + l4 * 4 + i;
      if (grow < M) C[(size_t)grow * N_CLS + n * 16 + l15] = acc[n][i] + bv;
    }
  }
}

// ---------------- propagation: one wave per node, 8 gathers in flight ----------------
__global__ __launch_bounds__(256) void prop_kernel(const float* __restrict__ zin,
    const float* __restrict__ x0, const float* __restrict__ selfw,
    const int* __restrict__ ptr, const int2* __restrict__ epack,
    float* __restrict__ zout) {
  int wid = (blockIdx.x * 256 + threadIdx.x) >> 6;
  int lane = threadIdx.x & 63;
  if (wid >= N_NODES) return;
  size_t base = (size_t)wid * 64 + lane;
  float acc = fmaf(selfw[wid], zin[base], ALPHA_V * x0[base]);
  int e = ptr[wid], e1 = ptr[wid + 1];

  // full batches of 8, all gathers issued before FMAs
  for (; e + 8 <= e1; e += 8) {
    int2 p[8];
#pragma unroll
    for (int j = 0; j < 8; ++j) p[j] = epack[e + j];
    float g[8];
#pragma unroll
    for (int j = 0; j < 8; ++j) g[j] = zin[(size_t)p[j].x * 64 + lane];
#pragma unroll
    for (int j = 0; j < 8; ++j) acc = fmaf(__int_as_float(p[j].y), g[j], acc);
  }
  // masked tail batch (keeps 8 loads in flight; dummies hit L1, w=0)
  if (e < e1) {
    int rem = e1 - e;
    int2 p[8];
#pragma unroll
    for (int j = 0; j < 8; ++j) p[j] = epack[(j < rem) ? e + j : e];
    float g[8];
#pragma unroll
    for (int j = 0; j < 8; ++j) g[j] = zin[(size_t)p[j].x * 64 + lane];
#pragma unroll
    for (int j = 0; j < 8; ++j) {
      float w = (j < rem) ? __int_as_float(p[j].y) : 0.0f;
      acc = fmaf(w, g[j], acc);
    }
  }
  zout[base] = acc;
}

// ---------------- host launcher ----------------
extern "C" void kernel_launch(void* const* d_in, const int* in_sizes, int n_in,
                              void* d_out, int out_size, void* d_ws, size_t ws_size,
                              hipStream_t stream) {
  const float* x  = (const float*)d_in[0];
  const float* W1 = (const float*)d_in[1];
  const float* b1 = (const float*)d_in[2];
  const float* W2 = (const float*)d_in[3];
  const float* b2 = (const float*)d_in[4];
  const int*   eb = (const int*)d_in[5];
  float* out = (float*)d_out;

  char* ws = (char*)d_ws;
  size_t off = 0;
  auto alloc = [&](size_t bytes) -> void* {
    void* p = ws + off;
    off = (off + bytes + 255) & ~(size_t)255;
    return p;
  };

  int*   flagp  = (int*)alloc(256);
  int*   cnt    = (int*)alloc(N_NODES * sizeof(int));
  int*   ptr    = (int*)alloc((N_NODES + 1) * sizeof(int));
  int*   cursor = (int*)alloc(N_NODES * sizeof(int));
  int*   bsum   = (int*)alloc(256 * sizeof(int));
  float* dinv   = (float*)alloc(N_NODES * sizeof(float));
  float* selfw  = (float*)alloc(N_NODES * sizeof(float));
  int2*  epack  = (int2*)alloc((size_t)N_EDGES * sizeof(int2));
  unsigned short* W1T = (unsigned short*)alloc((size_t)HID * F_INDIM * sizeof(unsigned short));
  unsigned short* W2T = (unsigned short*)alloc((size_t)N_CLS * HID * sizeof(unsigned short));
  float* x0     = (float*)alloc((size_t)N_NODES * N_CLS * sizeof(float));
  float* zB     = (float*)alloc((size_t)N_NODES * N_CLS * sizeof(float));

  int nchunks = 1;
  while (nchunks < 16) {
    size_t hbytes = (size_t)(N_NODES / nchunks) * HID * sizeof(unsigned short);
    if (off + hbytes <= ws_size) break;
    nchunks <<= 1;
  }
  int Mc = N_NODES / nchunks;
  unsigned short* h = (unsigned short*)alloc((size_t)Mc * HID * sizeof(unsigned short));

  hipMemsetAsync(cnt, 0, N_NODES * sizeof(int), stream);
  detect_kernel<<<1, 256, 0, stream>>>(eb, flagp);
  count_kernel<<<(N_EDGES + 255) / 256, 256, 0, stream>>>(eb, flagp, cnt);
  int nblk = (N_NODES + 255) / 256;
  scan1_kernel<<<nblk, 256, 0, stream>>>(cnt, ptr, bsum);
  scan2_kernel<<<1, 256, 0, stream>>>(bsum, nblk);
  scan3_kernel<<<nblk, 256, 0, stream>>>(ptr, bsum);
  dinv_kernel<<<nblk, 256, 0, stream>>>(cnt, ptr, dinv, selfw, cursor);
  fill_kernel<<<(N_EDGES + 255) / 256, 256, 0, stream>>>(eb, flagp, dinv, cursor, epack);
  prep_w<<<(F_INDIM * HID + HID * N_CLS + 255) / 256, 256, 0, stream>>>(W1, W2, W1T, W2T);

  for (int ci = 0; ci < nchunks; ++ci) {
    const float* Achunk = x + (size_t)ci * Mc * F_INDIM;
    dim3 g1((Mc + 127) / 128, HID / 128);
    gemm1_mfma<<<g1, 256, 0, stream>>>(Achunk, W1T, b1, h, Mc);
    dim3 g2((Mc + 63) / 64, 1);
    gemm2_mfma<<<g2, 256, 0, stream>>>(h, W2T, b2, x0 + (size_t)ci * Mc * N_CLS, Mc);
  }

  int pgrid = (N_NODES * 64) / 256;
  const float* zin = x0;
  float* zout = zB;
  for (int s = 0; s < K_STEPS; ++s) {
    prop_kernel<<<pgrid, 256, 0, stream>>>(zin, x0, selfw, ptr, epack, zout);
    zin = zout;
    zout = (zout == zB) ? out : zB;
  }
}

// Round 4
// 443.549 us; speedup vs baseline: 2.4582x; 1.1288x over previous
//
#include <hip/hip_runtime.h>

#define N_NODES 50000
#define N_EDGES 800000
#define F_INDIM 512
#define HID     256
#define N_CLS   64
#define K_STEPS 10
#define ALPHA_V 0.1f

typedef __attribute__((ext_vector_type(8))) short short8;
typedef __attribute__((ext_vector_type(4))) float f32x4;
typedef __attribute__((ext_vector_type(4))) unsigned short ushort4v;

__device__ __forceinline__ unsigned short f2bf(float f) {
  unsigned u = __builtin_bit_cast(unsigned, f);
  unsigned r = (u + 0x7fffu + ((u >> 16) & 1u)) >> 16;
  return (unsigned short)r;
}
__device__ __forceinline__ float bflo(unsigned g) {  // low bf16 of packed uint
  return __builtin_bit_cast(float, g << 16);
}
__device__ __forceinline__ float bfhi(unsigned g) {  // high bf16
  return __builtin_bit_cast(float, g & 0xffff0000u);
}

#define GLOAD_LDS16(g, l)                                                        \
  __builtin_amdgcn_global_load_lds(                                              \
      (const __attribute__((address_space(1))) unsigned int*)(g),                \
      (__attribute__((address_space(3))) unsigned int*)(l), 16, 0, 0)

// ---------------- edge dtype detection ----------------
__global__ void detect_kernel(const int* __restrict__ eb, int* __restrict__ flag) {
  __shared__ int any;
  if (threadIdx.x == 0) any = 0;
  __syncthreads();
  for (int j = threadIdx.x; j < 1024; j += 256) {
    if (eb[2 * j + 1] != 0) atomicOr(&any, 1);
  }
  __syncthreads();
  if (threadIdx.x == 0) flag[0] = any ? 0 : 1;  // 1 => int64 stride, 0 => int32
}

// ---------------- degree histogram over targets ----------------
__global__ void count_kernel(const int* __restrict__ eb, const int* __restrict__ flagp,
                             int* __restrict__ cnt) {
  int e = blockIdx.x * 256 + threadIdx.x;
  if (e >= N_EDGES) return;
  int sh = flagp[0];
  int c = eb[((size_t)(N_EDGES + e)) << sh];
  atomicAdd(&cnt[c], 1);
}

// ---------------- 3-kernel exclusive scan ----------------
__global__ void scan1_kernel(const int* __restrict__ cnt, int* __restrict__ ptr,
                             int* __restrict__ bsum) {
  __shared__ int sm[256];
  int t = threadIdx.x;
  int i = blockIdx.x * 256 + t;
  int v = (i < N_NODES) ? cnt[i] : 0;
  sm[t] = v;
  __syncthreads();
  for (int off = 1; off < 256; off <<= 1) {
    int x = sm[t];
    if (t >= off) x += sm[t - off];
    __syncthreads();
    sm[t] = x;
    __syncthreads();
  }
  int incl = sm[t];
  if (i < N_NODES) ptr[i] = incl - v;
  if (t == 255) bsum[blockIdx.x] = incl;
}

__global__ void scan2_kernel(int* __restrict__ bsum, int nblk) {
  __shared__ int sm[256];
  int t = threadIdx.x;
  int v = (t < nblk) ? bsum[t] : 0;
  sm[t] = v;
  __syncthreads();
  for (int off = 1; off < 256; off <<= 1) {
    int x = sm[t];
    if (t >= off) x += sm[t - off];
    __syncthreads();
    sm[t] = x;
    __syncthreads();
  }
  int incl = sm[t];
  if (t < nblk) bsum[t] = incl - v;
}

__global__ void scan3_kernel(int* __restrict__ ptr, const int* __restrict__ bsum) {
  int i = blockIdx.x * 256 + threadIdx.x;
  if (i < N_NODES) ptr[i] += bsum[i >> 8];
  if (i == 0) ptr[N_NODES] = N_EDGES;
}

// ---------------- dinv + selfw + cursor init ----------------
__global__ void dinv_kernel(const int* __restrict__ cnt, const int* __restrict__ ptr,
                            float* __restrict__ dinv, float* __restrict__ selfw,
                            int* __restrict__ cursor) {
  int i = blockIdx.x * 256 + threadIdx.x;
  if (i >= N_NODES) return;
  float di = rsqrtf((float)cnt[i] + 1.0f);
  dinv[i] = di;
  selfw[i] = (1.0f - ALPHA_V) * di * di;
  cursor[i] = ptr[i];
}

// ---------------- CSR fill (by target), packed (src, weight) ----------------
__global__ void fill_kernel(const int* __restrict__ eb, const int* __restrict__ flagp,
                            const float* __restrict__ dinv, int* __restrict__ cursor,
                            int2* __restrict__ epack) {
  int e = blockIdx.x * 256 + threadIdx.x;
  if (e >= N_EDGES) return;
  int sh = flagp[0];
  int r = eb[((size_t)e) << sh];
  int c = eb[((size_t)(N_EDGES + e)) << sh];
  int pos = atomicAdd(&cursor[c], 1);
  float w = (1.0f - ALPHA_V) * dinv[r] * dinv[c];
  epack[pos] = make_int2(r, __float_as_int(w));
}

// ---------------- weight transpose + bf16 prepass ----------------
__global__ void prep_w(const float* __restrict__ W1, const float* __restrict__ W2,
                       unsigned short* __restrict__ W1T, unsigned short* __restrict__ W2T) {
  int i = blockIdx.x * 256 + threadIdx.x;
  if (i < F_INDIM * HID) {
    int k = i >> 8, c = i & 255;
    W1T[(size_t)c * F_INDIM + k] = f2bf(W1[i]);
  }
  int j = i - F_INDIM * HID;
  if (j >= 0 && j < HID * N_CLS) {
    int k = j >> 6, c = j & 63;
    W2T[(size_t)c * HID + k] = f2bf(W2[j]);
  }
}

// ---------------- GEMM1: h = relu(x @ W1 + b1), bf16 MFMA ----------------
// BM=64, BN=128, BK=32. A fp32 loaded as contiguous 1KB/wave chunks -> in-reg
// cvt -> swizzled ds_write. B via global_load_lds with pre-swizzled source.
// Swizzle: 16B granule g' = g ^ ((row>>1)&3)  => <=2-way conflicts on b128.
__global__ __launch_bounds__(256, 4) void gemm1_mfma(
    const float* __restrict__ A, const unsigned short* __restrict__ BT,
    const float* __restrict__ bias, unsigned short* __restrict__ H, int M) {
  __shared__ unsigned short Ab[2][64 * 32];    // 4 KB each
  __shared__ unsigned short Bb[2][128 * 32];   // 8 KB each
  const int t = threadIdx.x;
  const int wave = t >> 6, lane = t & 63;
  const int l15 = lane & 15, l4 = lane >> 4;
  const int row0 = blockIdx.x * 64, col0 = blockIdx.y * 128;

  f32x4 acc[8];
#pragma unroll
  for (int n = 0; n < 8; ++n) acc[n] = (f32x4)0.0f;

  const int NT = F_INDIM / 32;  // 16

  // B staging: 2 glds instructions per wave, each 1024 B linear LDS.
  auto stageB = [&](int buf, int kt) {
#pragma unroll
    for (int i = 0; i < 2; ++i) {
      int row = wave * 32 + i * 16 + (lane >> 2);  // B-tile row = output col
      int g = lane & 3;
      int kg = g ^ ((row >> 1) & 3);
      const unsigned short* src = BT + (size_t)(col0 + row) * F_INDIM + kt * 32 + kg * 8;
      unsigned short* dst = &Bb[buf][(wave * 32 + i * 16) * 32];  // wave-uniform
      GLOAD_LDS16(src, dst);
    }
  };
  // A: 2 contiguous f32x4 per lane (1024 B per wave instr).
  f32x4 ar[2];
  int arow[2], acol[2];
  auto loadA = [&](int kt) {
#pragma unroll
    for (int i = 0; i < 2; ++i) {
      int idx = wave * 512 + i * 256 + lane * 4;   // flat float idx in 64x32 tile
      int row = idx >> 5;
      int col = idx & 31;
      arow[i] = row; acol[i] = col;
      int gr = row0 + row;
      if (gr > M - 1) gr = M - 1;
      ar[i] = *(const f32x4*)(A + (size_t)gr * F_INDIM + kt * 32 + col);
    }
  };
  auto writeA = [&](int buf) {
#pragma unroll
    for (int i = 0; i < 2; ++i) {
      int row = arow[i], col = acol[i];
      int g = col >> 3;                 // 16B granule within row
      int gp = g ^ ((row >> 1) & 3);
      ushort4v o;
#pragma unroll
      for (int j = 0; j < 4; ++j) o[j] = f2bf(ar[i][j]);
      *(ushort4v*)(&Ab[buf][row * 32 + gp * 8 + (col & 7)]) = o;
    }
  };
  auto compute = [&](int buf) {
    int rowA = wave * 16 + l15;
    short8 af = *(const short8*)(&Ab[buf][rowA * 32 + (l4 ^ ((rowA >> 1) & 3)) * 8]);
    short8 bf[8];
#pragma unroll
    for (int n = 0; n < 8; ++n) {
      int c = n * 16 + l15;
      bf[n] = *(const short8*)(&Bb[buf][c * 32 + (l4 ^ ((c >> 1) & 3)) * 8]);
    }
#pragma unroll
    for (int n = 0; n < 8; ++n)
      acc[n] = __builtin_amdgcn_mfma_f32_16x16x32_bf16(af, bf[n], acc[n], 0, 0, 0);
  };

  stageB(0, 0);
  loadA(0);
  writeA(0);
  __syncthreads();
#pragma unroll 4
  for (int kt = 0; kt < NT; ++kt) {
    int cur = kt & 1;
    if (kt + 1 < NT) {
      stageB(cur ^ 1, kt + 1);
      loadA(kt + 1);
    }
    compute(cur);
    if (kt + 1 < NT) writeA(cur ^ 1);
    __syncthreads();
  }

  float bv[8];
#pragma unroll
  for (int n = 0; n < 8; ++n) bv[n] = bias[col0 + n * 16 + l15];
#pragma unroll
  for (int i = 0; i < 4; ++i) {
    int grow = row0 + wave * 16 + l4 * 4 + i;
    if (grow >= M) continue;
#pragma unroll
    for (int n = 0; n < 8; ++n) {
      int gcol = col0 + n * 16 + l15;
      float v = fmaxf(acc[n][i] + bv[n], 0.0f);
      H[(size_t)grow * HID + gcol] = f2bf(v);
    }
  }
}

// ---------------- GEMM2: x0 = h @ W2 + b2 (fp32 + bf16 outputs) ----------------
__global__ __launch_bounds__(256) void gemm2_mfma(
    const unsigned short* __restrict__ Hm, const unsigned short* __restrict__ BT,
    const float* __restrict__ bias, float* __restrict__ C,
    unsigned short* __restrict__ Ch, int M) {
  const int t = threadIdx.x;
  const int wave = t >> 6, lane = t & 63;
  const int l15 = lane & 15, l4 = lane >> 4;
  const int row0 = blockIdx.x * 64 + wave * 16;

  f32x4 acc[4];
#pragma unroll
  for (int n = 0; n < 4; ++n) acc[n] = (f32x4)0.0f;

  int gr = row0 + l15;
  if (gr > M - 1) gr = M - 1;
  const unsigned short* arow = Hm + (size_t)gr * HID + l4 * 8;

#pragma unroll
  for (int kt = 0; kt < HID / 32; ++kt) {
    short8 af = *(const short8*)(arow + kt * 32);
    short8 bf[4];
#pragma unroll
    for (int n = 0; n < 4; ++n)
      bf[n] = *(const short8*)(BT + (size_t)(n * 16 + l15) * HID + kt * 32 + l4 * 8);
#pragma unroll
    for (int n = 0; n < 4; ++n)
      acc[n] = __builtin_amdgcn_mfma_f32_16x16x32_bf16(af, bf[n], acc[n], 0, 0, 0);
  }

#pragma unroll
  for (int n = 0; n < 4; ++n) {
    float bv = bias[n * 16 + l15];
#pragma unroll
    for (int i = 0; i < 4; ++i) {
      int grow = row0 + l4 * 4 + i;
      if (grow < M) {
        float v = acc[n][i] + bv;
        C[(size_t)grow * N_CLS + n * 16 + l15] = v;
        Ch[(size_t)grow * N_CLS + n * 16 + l15] = f2bf(v);
      }
    }
  }
}

// ---------------- propagation: bf16 z, 2 edges per gather instruction ----------------
// Lane l: half = l>>5 handles edges e+2j+half; cl = l&31 owns channels 2cl,2cl+1
// (one packed uint of the 128-B bf16 row). fp32 accumulate; cross-half combine
// via shfl_xor(32); lanes 0-31 store packed bf16 (or float2 on last step).
template <bool LAST>
__global__ __launch_bounds__(256) void prop_step(
    const unsigned int* __restrict__ zin32, const float* __restrict__ x0f,
    const float* __restrict__ selfw, const int* __restrict__ ptr,
    const int2* __restrict__ epack, unsigned int* __restrict__ zout32,
    float* __restrict__ outf) {
  int wid = (blockIdx.x * 256 + threadIdx.x) >> 6;
  int lane = threadIdx.x & 63;
  if (wid >= N_NODES) return;
  const int half = lane >> 5, cl = lane & 31;

  float a0 = 0.0f, a1 = 0.0f;
  if (half == 0) {
    unsigned zs = zin32[(size_t)wid * 32 + cl];
    float sw = selfw[wid];
    float2 xv = *(const float2*)(x0f + (size_t)wid * 64 + 2 * cl);
    a0 = fmaf(sw, bflo(zs), ALPHA_V * xv.x);
    a1 = fmaf(sw, bfhi(zs), ALPHA_V * xv.y);
  }

  int e = ptr[wid], e1 = ptr[wid + 1];
  for (; e + 16 <= e1; e += 16) {
    int2 p[8];
#pragma unroll
    for (int j = 0; j < 8; ++j) p[j] = epack[e + 2 * j + half];
    unsigned g[8];
#pragma unroll
    for (int j = 0; j < 8; ++j) g[j] = zin32[(size_t)p[j].x * 32 + cl];
#pragma unroll
    for (int j = 0; j < 8; ++j) {
      float w = __int_as_float(p[j].y);
      a0 = fmaf(w, bflo(g[j]), a0);
      a1 = fmaf(w, bfhi(g[j]), a1);
    }
  }
  if (e < e1) {
    int2 p[8];
    float wv[8];
#pragma unroll
    for (int j = 0; j < 8; ++j) {
      int idx = e + 2 * j + half;
      bool ok = idx < e1;
      p[j] = epack[ok ? idx : e];
      wv[j] = ok ? 1.0f : 0.0f;
    }
    unsigned g[8];
#pragma unroll
    for (int j = 0; j < 8; ++j) g[j] = zin32[(size_t)p[j].x * 32 + cl];
#pragma unroll
    for (int j = 0; j < 8; ++j) {
      float w = wv[j] * __int_as_float(p[j].y);
      a0 = fmaf(w, bflo(g[j]), a0);
      a1 = fmaf(w, bfhi(g[j]), a1);
    }
  }

  a0 += __shfl_xor(a0, 32);
  a1 += __shfl_xor(a1, 32);

  if (half == 0) {
    if (LAST) {
      *(float2*)(outf + (size_t)wid * 64 + 2 * cl) = make_float2(a0, a1);
    } else {
      unsigned packed = (unsigned)f2bf(a0) | ((unsigned)f2bf(a1) << 16);
      zout32[(size_t)wid * 32 + cl] = packed;
    }
  }
}

// ---------------- host launcher ----------------
extern "C" void kernel_launch(void* const* d_in, const int* in_sizes, int n_in,
                              void* d_out, int out_size, void* d_ws, size_t ws_size,
                              hipStream_t stream) {
  const float* x  = (const float*)d_in[0];
  const float* W1 = (const float*)d_in[1];
  const float* b1 = (const float*)d_in[2];
  const float* W2 = (const float*)d_in[3];
  const float* b2 = (const float*)d_in[4];
  const int*   eb = (const int*)d_in[5];
  float* out = (float*)d_out;

  char* ws = (char*)d_ws;
  size_t off = 0;
  auto alloc = [&](size_t bytes) -> void* {
    void* p = ws + off;
    off = (off + bytes + 255) & ~(size_t)255;
    return p;
  };

  int*   flagp  = (int*)alloc(256);
  int*   cnt    = (int*)alloc(N_NODES * sizeof(int));
  int*   ptr    = (int*)alloc((N_NODES + 1) * sizeof(int));
  int*   cursor = (int*)alloc(N_NODES * sizeof(int));
  int*   bsum   = (int*)alloc(256 * sizeof(int));
  float* dinv   = (float*)alloc(N_NODES * sizeof(float));
  float* selfw  = (float*)alloc(N_NODES * sizeof(float));
  int2*  epack  = (int2*)alloc((size_t)N_EDGES * sizeof(int2));
  unsigned short* W1T = (unsigned short*)alloc((size_t)HID * F_INDIM * sizeof(unsigned short));
  unsigned short* W2T = (unsigned short*)alloc((size_t)N_CLS * HID * sizeof(unsigned short));
  float* x0f    = (float*)alloc((size_t)N_NODES * N_CLS * sizeof(float));
  unsigned int* x0h = (unsigned int*)alloc((size_t)N_NODES * 32 * sizeof(unsigned int));
  unsigned int* z1  = (unsigned int*)alloc((size_t)N_NODES * 32 * sizeof(unsigned int));
  unsigned int* z2  = (unsigned int*)alloc((size_t)N_NODES * 32 * sizeof(unsigned int));

  int nchunks = 1;
  while (nchunks < 16) {
    size_t hbytes = (size_t)(N_NODES / nchunks) * HID * sizeof(unsigned short);
    if (off + hbytes <= ws_size) break;
    nchunks <<= 1;
  }
  int Mc = N_NODES / nchunks;
  unsigned short* h = (unsigned short*)alloc((size_t)Mc * HID * sizeof(unsigned short));

  hipMemsetAsync(cnt, 0, N_NODES * sizeof(int), stream);
  detect_kernel<<<1, 256, 0, stream>>>(eb, flagp);
  count_kernel<<<(N_EDGES + 255) / 256, 256, 0, stream>>>(eb, flagp, cnt);
  int nblk = (N_NODES + 255) / 256;
  scan1_kernel<<<nblk, 256, 0, stream>>>(cnt, ptr, bsum);
  scan2_kernel<<<1, 256, 0, stream>>>(bsum, nblk);
  scan3_kernel<<<nblk, 256, 0, stream>>>(ptr, bsum);
  dinv_kernel<<<nblk, 256, 0, stream>>>(cnt, ptr, dinv, selfw, cursor);
  fill_kernel<<<(N_EDGES + 255) / 256, 256, 0, stream>>>(eb, flagp, dinv, cursor, epack);
  prep_w<<<(F_INDIM * HID + HID * N_CLS + 255) / 256, 256, 0, stream>>>(W1, W2, W1T, W2T);

  for (int ci = 0; ci < nchunks; ++ci) {
    const float* Achunk = x + (size_t)ci * Mc * F_INDIM;
    dim3 g1((Mc + 63) / 64, HID / 128);
    gemm1_mfma<<<g1, 256, 0, stream>>>(Achunk, W1T, b1, h, Mc);
    dim3 g2((Mc + 63) / 64, 1);
    gemm2_mfma<<<g2, 256, 0, stream>>>(h, W2T, b2,
        x0f + (size_t)ci * Mc * N_CLS,
        (unsigned short*)(x0h + (size_t)ci * Mc * 32), Mc);
  }

  int pgrid = (N_NODES + 3) / 4;  // 4 waves (nodes) per 256-thread block
  const unsigned int* zin = x0h;
  unsigned int* zo[2] = {z1, z2};
  for (int s = 0; s < K_STEPS - 1; ++s) {
    unsigned int* zout = zo[s & 1];
    prop_step<false><<<pgrid, 256, 0, stream>>>(zin, x0f, selfw, ptr, epack, zout, nullptr);
    zin = zout;
  }
  prop_step<true><<<pgrid, 256, 0, stream>>>(zin, x0f, selfw, ptr, epack, nullptr, out);
}